// Round 14
// baseline (278.670 us; speedup 1.0000x reference)
//
#include <hip/hip_runtime.h>
#include <stdint.h>

// B=4, N=8192, F=64, L=2:  z = x; 2x: z = relu(A @ z @ W_l)  ==  relu(A @ (z @ W_l))
// Base = r13 (167.7us). ONE change: gemm1 BK 64->32 => LDS 128->64 KiB => 2 blocks/CU.
//   r9: gemm1 1 block/CU, phases additively serial (load 2.6 + mfma 0.9 + stage 1.1 us/tile).
//   Cross-block overlap is the untried mechanism (intra-block ledgers 0-for-2).
//   Swizzle in 4-octet space: stored pos = oct ^ (row&3) (2-way bank = free).
//   Epilogue in two 64KiB halves (keeps static LDS at 64KiB).
// Pipeline: zw0 -> gemm1(fused cvt) -> zw1P -> gemm2 -> combineF
// ws: [0,128Mi) Ab | [128Mi,+4Mi) Zt | [136Mi,+32Mi) P (bf16 [8][8192][256])

#define MK 8192

typedef float f32x4 __attribute__((ext_vector_type(4)));
typedef uint32_t u32x4 __attribute__((ext_vector_type(4)));
typedef uint32_t u32x2 __attribute__((ext_vector_type(2)));
typedef __bf16 bf16x8 __attribute__((ext_vector_type(8)));

__device__ inline uint16_t f2bf(float f) {
  uint32_t u = __builtin_bit_cast(uint32_t, f);
  u += 0x7fffu + ((u >> 16) & 1u);   // RNE (finite randn inputs)
  return (uint16_t)(u >> 16);
}
__device__ inline float bf2f(uint32_t lo16) {
  return __builtin_bit_cast(float, lo16 << 16);
}

#define GLD(src, dstbase)                                                                    \
  __builtin_amdgcn_global_load_lds((const __attribute__((address_space(1))) uint32_t*)(src), \
                                   (__attribute__((address_space(3))) uint32_t*)(dstbase),   \
                                   16, 0, 0)

// ---------------- zw0: Zt = (x @ W0)^T ----------------------------------------------------
__global__ __launch_bounds__(256) void zw0(const float* __restrict__ x,
                                           const float* __restrict__ net,
                                           uint16_t* __restrict__ Zt) {
  __shared__ float Wl[64 * 64];
  __shared__ float rows[64][65];
  const int b = blockIdx.y, n0 = blockIdx.x * 64, tid = threadIdx.x;
  for (int i = tid * 4; i < 4096; i += 1024) {
    f32x4 v = *(const f32x4*)(net + i);
    Wl[i] = v[0]; Wl[i + 1] = v[1]; Wl[i + 2] = v[2]; Wl[i + 3] = v[3];
  }
  const float* src = x + ((uint64_t)b * MK + n0) * 64;
  for (int i = tid * 4; i < 4096; i += 1024) {
    f32x4 v = *(const f32x4*)(src + i);
    int r = i >> 6, f = i & 63;
    rows[r][f] = v[0]; rows[r][f + 1] = v[1]; rows[r][f + 2] = v[2]; rows[r][f + 3] = v[3];
  }
  __syncthreads();
  const int nl = tid & 63, g0 = (tid >> 6) * 16;
  float s[16];
#pragma unroll
  for (int j = 0; j < 16; ++j) s[j] = 0.f;
  for (int f = 0; f < 64; ++f) {
    float rv = rows[nl][f];
#pragma unroll
    for (int j = 0; j < 16; ++j) s[j] = fmaf(rv, Wl[f * 64 + g0 + j], s[j]);
  }
  uint16_t* dst = Zt + (uint64_t)(b * 64 + g0) * MK + n0 + nl;
#pragma unroll
  for (int j = 0; j < 16; ++j) dst[(uint64_t)j * MK] = f2bf(s[j]);
}

// ---------------- gemm1: BK=32, 64KiB LDS, 2 blocks/CU, fused NT-f32 cvt ------------------
__global__ __launch_bounds__(512, 2) void gemm1(const float* __restrict__ Af,
                                                const uint16_t* __restrict__ Bt,
                                                uint16_t* __restrict__ Ab,
                                                uint16_t* __restrict__ P) {
  __shared__ __align__(16) uint16_t LB[32768];   // 64 KiB total
#define AS1(b) (LB + (b)*8192)                    // 256r x 32k bf16 = 16 KiB per buf
#define BS1(b) (LB + 16384 + (b)*8192)
  const int bid = (int)blockIdx.x;
  const int s = bid & 7, bm = bid >> 3;
  const int row0 = bm * 256, k0 = s * 1024;       // 32 tiles of BK=32
  const int tid = threadIdx.x, wid = tid >> 6, lane = tid & 63;
  const int wr = wid >> 2, wc = wid & 3;

  // A staging: thread -> row tid>>1, 16-col half tid&1 (4x f32x4 NT = 64B)
  const int ar = tid >> 1, h = tid & 1;
  const float* gA = Af + (uint64_t)(row0 + ar) * MK + k0 + h * 16;
  uint16_t* AbW = Ab + (uint64_t)(row0 + ar) * MK + k0 + h * 16;

  // B staging via GLD: chunk = 16r x 32k = 1KB; wave wid -> chunks 2wid, 2wid+1
  const int brow = lane >> 2, bpos = lane & 3, bsrc = bpos ^ (brow & 3);
  const uint16_t* gBa = Bt + (uint64_t)((2 * wid) * 16 + brow) * MK + k0 + bsrc * 8;
  const uint16_t* gBb = Bt + (uint64_t)((2 * wid + 1) * 16 + brow) * MK + k0 + bsrc * 8;
  const int lBa = (2 * wid) * 512, lBb = (2 * wid + 1) * 512;

  f32x4 acc[8][4] = {};
  f32x4 rv[4];

  auto loadA = [&](int kofs) {
#pragma unroll
    for (int j = 0; j < 4; ++j)
      rv[j] = __builtin_nontemporal_load((const f32x4*)(gA + kofs + j * 4));
  };
  auto stageA = [&](int buf, int kofs) {
    u32x4 w0, w1;
    w0[0] = (uint32_t)f2bf(rv[0][0]) | ((uint32_t)f2bf(rv[0][1]) << 16);
    w0[1] = (uint32_t)f2bf(rv[0][2]) | ((uint32_t)f2bf(rv[0][3]) << 16);
    w0[2] = (uint32_t)f2bf(rv[1][0]) | ((uint32_t)f2bf(rv[1][1]) << 16);
    w0[3] = (uint32_t)f2bf(rv[1][2]) | ((uint32_t)f2bf(rv[1][3]) << 16);
    w1[0] = (uint32_t)f2bf(rv[2][0]) | ((uint32_t)f2bf(rv[2][1]) << 16);
    w1[1] = (uint32_t)f2bf(rv[2][2]) | ((uint32_t)f2bf(rv[2][3]) << 16);
    w1[2] = (uint32_t)f2bf(rv[3][0]) | ((uint32_t)f2bf(rv[3][1]) << 16);
    w1[3] = (uint32_t)f2bf(rv[3][2]) | ((uint32_t)f2bf(rv[3][3]) << 16);
    const int o0 = 2 * h, o1 = 2 * h + 1;
    *(u32x4*)&AS1(buf)[ar * 32 + ((o0 ^ (ar & 3)) << 3)] = w0;
    *(u32x4*)&AS1(buf)[ar * 32 + ((o1 ^ (ar & 3)) << 3)] = w1;
    *(u32x4*)(AbW + kofs) = w0;
    *(u32x4*)(AbW + kofs + 8) = w1;
  };
  auto stageB = [&](int buf, int kofs) {
    GLD(gBa + kofs, &BS1(buf)[lBa]);
    GLD(gBb + kofs, &BS1(buf)[lBb]);
  };
  auto compute = [&](int buf) {
    const int fr = lane & 15, fk = lane >> 4;
    bf16x8 a[8], b[4];
#pragma unroll
    for (int mi = 0; mi < 8; ++mi) {
      const int r = wr * 128 + mi * 16 + fr;
      a[mi] = *(const bf16x8*)&AS1(buf)[r * 32 + ((fk ^ (r & 3)) << 3)];
    }
#pragma unroll
    for (int n = 0; n < 4; ++n) {
      const int r = wc * 64 + n * 16 + fr;
      b[n] = *(const bf16x8*)&BS1(buf)[r * 32 + ((fk ^ (r & 3)) << 3)];
    }
#pragma unroll
    for (int mi = 0; mi < 8; ++mi)
#pragma unroll
      for (int n = 0; n < 4; ++n)
        acc[mi][n] = __builtin_amdgcn_mfma_f32_16x16x32_bf16(a[mi], b[n], acc[mi][n], 0, 0, 0);
  };

  loadA(0);
  stageB(0, 0);
  stageA(0, 0);
  __syncthreads();

  int buf = 0;
  for (int t = 0; t < 32; ++t) {
    const int nxt = (t + 1) * 32;
    if (t < 31) { loadA(nxt); stageB(buf ^ 1, nxt); }
    compute(buf);
    if (t < 31) stageA(buf ^ 1, nxt);
    __syncthreads();
    buf ^= 1;
  }

  // ---- epilogue: two 64KiB halves, full-line P stores ----
  uint16_t* Pp = P + (uint64_t)s * 2097152 + (uint64_t)row0 * 256;
  const int lr = (lane >> 4) * 4, lc = lane & 15;
#pragma unroll
  for (int half = 0; half < 2; ++half) {
    __syncthreads();
    if (wr == half) {
#pragma unroll
      for (int mi = 0; mi < 8; ++mi)
#pragma unroll
        for (int n = 0; n < 4; ++n)
#pragma unroll
          for (int j = 0; j < 4; ++j)
            LB[(mi * 16 + lr + j) * 256 + (wc * 64 + n * 16 + lc)] = f2bf(acc[mi][n][j]);
    }
    __syncthreads();
#pragma unroll
    for (int i = 0; i < 8; ++i) {
      u32x4 v = *(const u32x4*)&LB[i * 4096 + tid * 8];
      *(u32x4*)(Pp + half * 32768 + i * 4096 + tid * 8) = v;
    }
  }
#undef AS1
#undef BS1
}

// ---------------- gemm2: counted-vmcnt loop + LDS-transpose epilogue (r13-exact) ----------
__global__ __launch_bounds__(512, 2) void gemm2(const uint16_t* __restrict__ Ab,
                                                const uint16_t* __restrict__ Bt,
                                                uint16_t* __restrict__ P) {
  __shared__ __align__(16) uint16_t LB[65536];
#define AS2(b) (LB + (b)*16384)
#define BS2(b) (LB + 32768 + (b)*16384)
  const int bid = (int)blockIdx.x;
  const int s = bid & 7, bm = bid >> 3;
  const int row0 = bm * 256, k0 = s * 1024;
  const int tid = threadIdx.x, wid = tid >> 6, lane = tid & 63;
  const int wr = wid >> 2, wc = wid & 3;

  const int lsub = lane >> 3;
  const int ksrc = ((lane & 7) ^ lsub) << 3;
  const uint16_t* gA0 = Ab + (uint64_t)(row0 + 4 * wid * 8 + lsub) * MK + k0 + ksrc;
  const uint16_t* gB0 = Bt + (uint64_t)(4 * wid * 8 + lsub) * MK + k0 + ksrc;
  const int lo = 4 * wid * 512;

  f32x4 acc[8][4] = {};

#pragma unroll
  for (int j = 0; j < 4; ++j) {
    GLD(gA0 + (uint64_t)j * 8 * MK, &AS2(0)[lo + j * 512]);
    GLD(gB0 + (uint64_t)j * 8 * MK, &BS2(0)[lo + j * 512]);
  }

  int buf = 0;
  for (int t = 0; t < 16; ++t) {
    const int tko = ((t + 1) < 16 ? (t + 1) : 15) * 64;
#pragma unroll
    for (int j = 0; j < 4; ++j) {
      GLD(gA0 + (uint64_t)j * 8 * MK + tko, &AS2(buf ^ 1)[lo + j * 512]);
      GLD(gB0 + (uint64_t)j * 8 * MK + tko, &BS2(buf ^ 1)[lo + j * 512]);
    }
    asm volatile("s_waitcnt vmcnt(8)" ::: "memory");
    __builtin_amdgcn_s_barrier();
    __builtin_amdgcn_sched_barrier(0);

    bf16x8 b[4][2];
#pragma unroll
    for (int n = 0; n < 4; ++n)
#pragma unroll
      for (int kk = 0; kk < 2; ++kk) {
        const int r = wc * 64 + n * 16 + (lane & 15);
        const int kb = kk * 4 + (lane >> 4);
        b[n][kk] = *(const bf16x8*)&BS2(buf)[r * 64 + ((kb ^ (r & 7)) << 3)];
      }
#pragma unroll
    for (int q = 0; q < 4; ++q) {
      bf16x8 a[2][2];
#pragma unroll
      for (int i = 0; i < 2; ++i)
#pragma unroll
        for (int kk = 0; kk < 2; ++kk) {
          const int r = wr * 128 + (2 * q + i) * 16 + (lane & 15);
          const int kb = kk * 4 + (lane >> 4);
          a[i][kk] = *(const bf16x8*)&AS2(buf)[r * 64 + ((kb ^ (r & 7)) << 3)];
        }
      __builtin_amdgcn_s_setprio(1);
#pragma unroll
      for (int kk = 0; kk < 2; ++kk)
#pragma unroll
        for (int i = 0; i < 2; ++i)
#pragma unroll
          for (int n = 0; n < 4; ++n)
            acc[2 * q + i][n] =
                __builtin_amdgcn_mfma_f32_16x16x32_bf16(a[i][kk], b[n][kk], acc[2 * q + i][n], 0, 0, 0);
      __builtin_amdgcn_s_setprio(0);
      __builtin_amdgcn_sched_barrier(0);
    }
    __builtin_amdgcn_s_barrier();
    buf ^= 1;
  }

  __syncthreads();
  const int lr = (lane >> 4) * 4, lc = lane & 15;
#pragma unroll
  for (int mi = 0; mi < 8; ++mi)
#pragma unroll
    for (int n = 0; n < 4; ++n)
#pragma unroll
      for (int j = 0; j < 4; ++j)
        LB[(wr * 128 + mi * 16 + lr + j) * 256 + (wc * 64 + n * 16 + lc)] = f2bf(acc[mi][n][j]);
  __syncthreads();
  uint16_t* Pp = P + (uint64_t)s * 2097152 + (uint64_t)row0 * 256;
#pragma unroll
  for (int i = 0; i < 16; ++i) {
    u32x4 v = *(const u32x4*)&LB[i * 4096 + tid * 8];
    *(u32x4*)(Pp + i * 4096 + tid * 8) = v;
  }
#undef AS2
#undef BS2
}

// ---------------- zw1P: rows = relu(sum_s P[s] (bf16)); Zt = rows @ W1 --------------------
__global__ __launch_bounds__(256) void zw1P(const uint16_t* __restrict__ P,
                                            const float* __restrict__ net,
                                            uint16_t* __restrict__ Zt) {
  __shared__ float Wl[64 * 64];
  __shared__ float rows[64][65];
  const int b = blockIdx.y, n0 = blockIdx.x * 64, tid = threadIdx.x;
  const float* Wsrc = net + 4096;
  for (int i = tid * 4; i < 4096; i += 1024) {
    f32x4 v = *(const f32x4*)(Wsrc + i);
    Wl[i] = v[0]; Wl[i + 1] = v[1]; Wl[i + 2] = v[2]; Wl[i + 3] = v[3];
  }
#pragma unroll
  for (int g = 0; g < 2; ++g) {
    const int idx = (tid + g * 256) * 8;
    const int r = idx >> 6, f0 = idx & 63;
    const uint16_t* base = P + (uint64_t)(n0 + r) * 256 + b * 64 + f0;
    float acc8[8] = {};
#pragma unroll
    for (int sp = 0; sp < 8; ++sp) {
      u32x4 v = *(const u32x4*)(base + (uint64_t)sp * 2097152);
#pragma unroll
      for (int j = 0; j < 4; ++j) {
        acc8[2 * j]     += bf2f(v[j] & 0xffffu);
        acc8[2 * j + 1] += bf2f(v[j] >> 16);
      }
    }
#pragma unroll
    for (int j = 0; j < 8; ++j) rows[r][f0 + j] = fmaxf(acc8[j], 0.0f);
  }
  __syncthreads();
  const int nl = tid & 63, g0 = (tid >> 6) * 16;
  float s[16];
#pragma unroll
  for (int j = 0; j < 16; ++j) s[j] = 0.f;
  for (int f = 0; f < 64; ++f) {
    float rv = rows[nl][f];
#pragma unroll
    for (int j = 0; j < 16; ++j) s[j] = fmaf(rv, Wl[f * 64 + g0 + j], s[j]);
  }
  uint16_t* dst = Zt + (uint64_t)(b * 64 + g0) * MK + n0 + nl;
#pragma unroll
  for (int j = 0; j < 16; ++j) dst[(uint64_t)j * MK] = f2bf(s[j]);
}

// ---------------- combineF: out = relu(sum_s P[s] (bf16)) -> f32 [4][8192][64] ------------
__global__ __launch_bounds__(256) void combineF(const uint16_t* __restrict__ P,
                                                float* __restrict__ out) {
  const uint64_t e = ((uint64_t)blockIdx.x * 256 + threadIdx.x) * 8;
  float acc8[8] = {};
#pragma unroll
  for (int sp = 0; sp < 8; ++sp) {
    u32x4 v = *(const u32x4*)&P[(uint64_t)sp * 2097152 + e];
#pragma unroll
    for (int j = 0; j < 4; ++j) {
      acc8[2 * j]     += bf2f(v[j] & 0xffffu);
      acc8[2 * j + 1] += bf2f(v[j] >> 16);
    }
  }
  const int m = (int)(e >> 8);
  const int c = (int)(e & 255);
  float* dst = &out[(((uint64_t)(c >> 6)) * MK + m) * 64 + (c & 63)];
  f32x4 w0, w1;
#pragma unroll
  for (int j = 0; j < 4; ++j) { w0[j] = fmaxf(acc8[j], 0.0f); w1[j] = fmaxf(acc8[4 + j], 0.0f); }
  *(f32x4*)dst = w0;
  *(f32x4*)(dst + 4) = w1;
}

extern "C" void kernel_launch(void* const* d_in, const int* in_sizes, int n_in,
                              void* d_out, int out_size, void* d_ws, size_t ws_size,
                              hipStream_t stream) {
  const float* x   = (const float*)d_in[0];
  const float* net = (const float*)d_in[2];
  const float* A   = (const float*)d_in[3];
  float* out = (float*)d_out;

  uint16_t* Ab = (uint16_t*)d_ws;                               // 128 MiB
  uint16_t* Zt = (uint16_t*)((char*)d_ws + 134217728ull);       // 4 MiB
  uint16_t* P  = (uint16_t*)((char*)d_ws + 142606336ull);       // 32 MiB (bf16 [8][8192][256])

  zw0<<<dim3(128, 4), dim3(256), 0, stream>>>(x, net, Zt);
  gemm1<<<dim3(256), dim3(512), 0, stream>>>(A, Zt, Ab, P);
  zw1P<<<dim3(128, 4), dim3(256), 0, stream>>>(P, net, Zt);
  gemm2<<<dim3(256), dim3(512), 0, stream>>>(Ab, Zt, P);
  combineF<<<dim3(1024), dim3(256), 0, stream>>>(P, out);
}

// Round 15
// 184.201 us; speedup vs baseline: 1.5129x; 1.5129x over previous
//
#include <hip/hip_runtime.h>
#include <stdint.h>

// B=4, N=8192, F=64, L=2:  z = x; 2x: z = relu(A @ z @ W_l)  ==  relu(A @ (z @ W_l))
// Base = r13 (167.7us). Change: both gemms go 8x1 waves (wave = 32 rows x 256 cols,
// acc[2][16]) so A-fragments are wave-private => A NEVER touches LDS. Ab is stored in
// fragment-chunk layout (1KB per (t,wid,mi,kk), lane-contiguous both directions):
//   off_u16(bm,s,t,wid,mi,kk,lane) = (bm*8+s)*262144 + (((t*8+wid)*2+mi)*2+kk)*512 + lane*8
// gemm1: NT f32 load -> cvt -> MFMA direct + chunk store. gemm2: chunk load -> MFMA.
// Accumulation order (t-major, kk inner) identical to r13 => bit-identical output.
// B path / staging / swizzle / LDS-transpose P epilogue / zw / combine: r13-exact.
// ws: [0,128Mi) Ab(blocked) | [128Mi,+4Mi) Zt | [136Mi,+32Mi) P (bf16 [8][8192][256])

#define MK 8192

typedef float f32x4 __attribute__((ext_vector_type(4)));
typedef uint32_t u32x4 __attribute__((ext_vector_type(4)));
typedef uint32_t u32x2 __attribute__((ext_vector_type(2)));
typedef __bf16 bf16x8 __attribute__((ext_vector_type(8)));

__device__ inline uint16_t f2bf(float f) {
  uint32_t u = __builtin_bit_cast(uint32_t, f);
  u += 0x7fffu + ((u >> 16) & 1u);   // RNE (finite randn inputs)
  return (uint16_t)(u >> 16);
}
__device__ inline float bf2f(uint32_t lo16) {
  return __builtin_bit_cast(float, lo16 << 16);
}

#define GLD(src, dstbase)                                                                    \
  __builtin_amdgcn_global_load_lds((const __attribute__((address_space(1))) uint32_t*)(src), \
                                   (__attribute__((address_space(3))) uint32_t*)(dstbase),   \
                                   16, 0, 0)
#define CHOFF(t, w, mi, kk) ((uint64_t)((((t)*8 + (w)) * 2 + (mi)) * 2 + (kk)) * 512)

// ---------------- zw0: Zt = (x @ W0)^T ----------------------------------------------------
__global__ __launch_bounds__(256) void zw0(const float* __restrict__ x,
                                           const float* __restrict__ net,
                                           uint16_t* __restrict__ Zt) {
  __shared__ float Wl[64 * 64];
  __shared__ float rows[64][65];
  const int b = blockIdx.y, n0 = blockIdx.x * 64, tid = threadIdx.x;
  for (int i = tid * 4; i < 4096; i += 1024) {
    f32x4 v = *(const f32x4*)(net + i);
    Wl[i] = v[0]; Wl[i + 1] = v[1]; Wl[i + 2] = v[2]; Wl[i + 3] = v[3];
  }
  const float* src = x + ((uint64_t)b * MK + n0) * 64;
  for (int i = tid * 4; i < 4096; i += 1024) {
    f32x4 v = *(const f32x4*)(src + i);
    int r = i >> 6, f = i & 63;
    rows[r][f] = v[0]; rows[r][f + 1] = v[1]; rows[r][f + 2] = v[2]; rows[r][f + 3] = v[3];
  }
  __syncthreads();
  const int nl = tid & 63, g0 = (tid >> 6) * 16;
  float s[16];
#pragma unroll
  for (int j = 0; j < 16; ++j) s[j] = 0.f;
  for (int f = 0; f < 64; ++f) {
    float rv = rows[nl][f];
#pragma unroll
    for (int j = 0; j < 16; ++j) s[j] = fmaf(rv, Wl[f * 64 + g0 + j], s[j]);
  }
  uint16_t* dst = Zt + (uint64_t)(b * 64 + g0) * MK + n0 + nl;
#pragma unroll
  for (int j = 0; j < 16; ++j) dst[(uint64_t)j * MK] = f2bf(s[j]);
}

// ---------------- gemm1: 8x1 waves, A reg-direct (no LDS), chunked Ab store ---------------
__global__ __launch_bounds__(512, 2) void gemm1(const float* __restrict__ Af,
                                                const uint16_t* __restrict__ Bt,
                                                uint16_t* __restrict__ Ab,
                                                uint16_t* __restrict__ P) {
  __shared__ __align__(16) uint16_t LB[65536];   // [0,32768) = Bs dbuf; full 128K for epilogue
#define BS1(b) (LB + (b)*16384)
  const int bid = (int)blockIdx.x;
  const int s = bid & 7, bm = bid >> 3;
  const int row0 = bm * 256, k0 = s * 1024;
  const int tid = threadIdx.x, wid = tid >> 6, lane = tid & 63;
  const int fr = lane & 15, fk = lane >> 4;

  // B staging (r13-exact): 32 chunks of 8r x 64k, 4/wave, pre-swizzled src
  const int lsub = lane >> 3;
  const int ksrc = ((lane & 7) ^ lsub) << 3;
  const uint16_t* gB0 = Bt + (uint64_t)(4 * wid * 8 + lsub) * MK + k0 + ksrc;
  const int lBo = 4 * wid * 512;

  // A direct: wave rows row0 + wid*32 + mi*16 + fr; k = k0 + t*64 + kk*32 + fk*8
  const float* gA[2];
#pragma unroll
  for (int mi = 0; mi < 2; ++mi)
    gA[mi] = Af + (uint64_t)(row0 + wid * 32 + mi * 16 + fr) * MK + k0 + fk * 8;
  uint16_t* AbR = Ab + (uint64_t)(bm * 8 + s) * 262144 + lane * 8;

  f32x4 acc[2][16] = {};
  f32x4 rv[2][2][2];
  bf16x8 a[2][2];

  auto loadA = [&](int t) {
#pragma unroll
    for (int mi = 0; mi < 2; ++mi)
#pragma unroll
      for (int kk = 0; kk < 2; ++kk) {
        rv[mi][kk][0] = __builtin_nontemporal_load((const f32x4*)(gA[mi] + t * 64 + kk * 32));
        rv[mi][kk][1] = __builtin_nontemporal_load((const f32x4*)(gA[mi] + t * 64 + kk * 32 + 4));
      }
  };
  auto cvtStoreA = [&](int t) {
#pragma unroll
    for (int mi = 0; mi < 2; ++mi)
#pragma unroll
      for (int kk = 0; kk < 2; ++kk) {
        u32x4 w;
        w[0] = (uint32_t)f2bf(rv[mi][kk][0][0]) | ((uint32_t)f2bf(rv[mi][kk][0][1]) << 16);
        w[1] = (uint32_t)f2bf(rv[mi][kk][0][2]) | ((uint32_t)f2bf(rv[mi][kk][0][3]) << 16);
        w[2] = (uint32_t)f2bf(rv[mi][kk][1][0]) | ((uint32_t)f2bf(rv[mi][kk][1][1]) << 16);
        w[3] = (uint32_t)f2bf(rv[mi][kk][1][2]) | ((uint32_t)f2bf(rv[mi][kk][1][3]) << 16);
        a[mi][kk] = __builtin_bit_cast(bf16x8, w);
        *(u32x4*)(AbR + CHOFF(t, wid, mi, kk)) = w;
      }
  };
  auto compute = [&](int buf) {
    const uint16_t* B = BS1(buf);
#pragma unroll
    for (int n = 0; n < 16; ++n) {
      const int r = n * 16 + fr, e = r & 7;
      bf16x8 b0 = *(const bf16x8*)&B[r * 64 + ((fk ^ e) << 3)];
      bf16x8 b1 = *(const bf16x8*)&B[r * 64 + (((4 + fk) ^ e) << 3)];
#pragma unroll
      for (int mi = 0; mi < 2; ++mi) {
        acc[mi][n] = __builtin_amdgcn_mfma_f32_16x16x32_bf16(a[mi][0], b0, acc[mi][n], 0, 0, 0);
        acc[mi][n] = __builtin_amdgcn_mfma_f32_16x16x32_bf16(a[mi][1], b1, acc[mi][n], 0, 0, 0);
      }
    }
  };

  // prologue: tile 0
  loadA(0);
#pragma unroll
  for (int j = 0; j < 4; ++j) GLD(gB0 + (uint64_t)j * 8 * MK, &BS1(0)[lBo + j * 512]);
  cvtStoreA(0);
  __syncthreads();

  int buf = 0;
  for (int t = 0; t < 16; ++t) {
    if (t < 15) {
      loadA(t + 1);
      const int nxt = (t + 1) * 64;
#pragma unroll
      for (int j = 0; j < 4; ++j) GLD(gB0 + (uint64_t)j * 8 * MK + nxt, &BS1(buf ^ 1)[lBo + j * 512]);
    }
    compute(buf);
    if (t < 15) cvtStoreA(t + 1);
    __syncthreads();
    buf ^= 1;
  }

  // epilogue (r13-style): LDS transpose -> full-line P stores
  const int lr = fk * 4, lc = fr;
#pragma unroll
  for (int mi = 0; mi < 2; ++mi)
#pragma unroll
    for (int n = 0; n < 16; ++n)
#pragma unroll
      for (int j = 0; j < 4; ++j)
        LB[(wid * 32 + mi * 16 + lr + j) * 256 + n * 16 + lc] = f2bf(acc[mi][n][j]);
  __syncthreads();
  uint16_t* Pp = P + (uint64_t)s * 2097152 + (uint64_t)row0 * 256;
#pragma unroll
  for (int i = 0; i < 16; ++i) {
    u32x4 v = *(const u32x4*)&LB[i * 4096 + tid * 8];
    *(u32x4*)(Pp + i * 4096 + tid * 8) = v;
  }
#undef BS1
}

// ---------------- gemm2: 8x1 waves, A from chunked Ab (reg-direct, L3) --------------------
__global__ __launch_bounds__(512, 2) void gemm2(const uint16_t* __restrict__ Ab,
                                                const uint16_t* __restrict__ Bt,
                                                uint16_t* __restrict__ P) {
  __shared__ __align__(16) uint16_t LB[65536];
#define BS2(b) (LB + (b)*16384)
  const int bid = (int)blockIdx.x;
  const int s = bid & 7, bm = bid >> 3;
  const int row0 = bm * 256, k0 = s * 1024;
  const int tid = threadIdx.x, wid = tid >> 6, lane = tid & 63;
  const int fr = lane & 15, fk = lane >> 4;

  const int lsub = lane >> 3;
  const int ksrc = ((lane & 7) ^ lsub) << 3;
  const uint16_t* gB0 = Bt + (uint64_t)(4 * wid * 8 + lsub) * MK + k0 + ksrc;
  const int lBo = 4 * wid * 512;
  const uint16_t* AbR = Ab + (uint64_t)(bm * 8 + s) * 262144 + lane * 8;

  f32x4 acc[2][16] = {};
  bf16x8 aC[2][2], aN[2][2];

  auto compute = [&](int buf, const bf16x8 (&a)[2][2]) {
    const uint16_t* B = BS2(buf);
#pragma unroll
    for (int n = 0; n < 16; ++n) {
      const int r = n * 16 + fr, e = r & 7;
      bf16x8 b0 = *(const bf16x8*)&B[r * 64 + ((fk ^ e) << 3)];
      bf16x8 b1 = *(const bf16x8*)&B[r * 64 + (((4 + fk) ^ e) << 3)];
#pragma unroll
      for (int mi = 0; mi < 2; ++mi) {
        acc[mi][n] = __builtin_amdgcn_mfma_f32_16x16x32_bf16(a[mi][0], b0, acc[mi][n], 0, 0, 0);
        acc[mi][n] = __builtin_amdgcn_mfma_f32_16x16x32_bf16(a[mi][1], b1, acc[mi][n], 0, 0, 0);
      }
    }
  };

  // prologue
#pragma unroll
  for (int mi = 0; mi < 2; ++mi)
#pragma unroll
    for (int kk = 0; kk < 2; ++kk)
      aC[mi][kk] = *(const bf16x8*)(AbR + CHOFF(0, wid, mi, kk));
#pragma unroll
  for (int j = 0; j < 4; ++j) GLD(gB0 + (uint64_t)j * 8 * MK, &BS2(0)[lBo + j * 512]);
  __syncthreads();

  for (int tt = 0; tt < 16; tt += 2) {
    // tile tt (buf 0): prefetch tt+1 -> aN
    {
      const int nxt = (tt + 1) * 64;
#pragma unroll
      for (int j = 0; j < 4; ++j) GLD(gB0 + (uint64_t)j * 8 * MK + nxt, &BS2(1)[lBo + j * 512]);
#pragma unroll
      for (int mi = 0; mi < 2; ++mi)
#pragma unroll
        for (int kk = 0; kk < 2; ++kk)
          aN[mi][kk] = *(const bf16x8*)(AbR + CHOFF(tt + 1, wid, mi, kk));
      compute(0, aC);
      __syncthreads();
    }
    // tile tt+1 (buf 1): prefetch tt+2 -> aC
    {
      if (tt + 2 < 16) {
        const int nxt = (tt + 2) * 64;
#pragma unroll
        for (int j = 0; j < 4; ++j) GLD(gB0 + (uint64_t)j * 8 * MK + nxt, &BS2(0)[lBo + j * 512]);
#pragma unroll
        for (int mi = 0; mi < 2; ++mi)
#pragma unroll
          for (int kk = 0; kk < 2; ++kk)
            aC[mi][kk] = *(const bf16x8*)(AbR + CHOFF(tt + 2, wid, mi, kk));
      }
      compute(1, aN);
      __syncthreads();
    }
  }

  const int lr = fk * 4, lc = fr;
#pragma unroll
  for (int mi = 0; mi < 2; ++mi)
#pragma unroll
    for (int n = 0; n < 16; ++n)
#pragma unroll
      for (int j = 0; j < 4; ++j)
        LB[(wid * 32 + mi * 16 + lr + j) * 256 + n * 16 + lc] = f2bf(acc[mi][n][j]);
  __syncthreads();
  uint16_t* Pp = P + (uint64_t)s * 2097152 + (uint64_t)row0 * 256;
#pragma unroll
  for (int i = 0; i < 16; ++i) {
    u32x4 v = *(const u32x4*)&LB[i * 4096 + tid * 8];
    *(u32x4*)(Pp + i * 4096 + tid * 8) = v;
  }
#undef BS2
}

// ---------------- zw1P: rows = relu(sum_s P[s] (bf16)); Zt = rows @ W1 --------------------
__global__ __launch_bounds__(256) void zw1P(const uint16_t* __restrict__ P,
                                            const float* __restrict__ net,
                                            uint16_t* __restrict__ Zt) {
  __shared__ float Wl[64 * 64];
  __shared__ float rows[64][65];
  const int b = blockIdx.y, n0 = blockIdx.x * 64, tid = threadIdx.x;
  const float* Wsrc = net + 4096;
  for (int i = tid * 4; i < 4096; i += 1024) {
    f32x4 v = *(const f32x4*)(Wsrc + i);
    Wl[i] = v[0]; Wl[i + 1] = v[1]; Wl[i + 2] = v[2]; Wl[i + 3] = v[3];
  }
#pragma unroll
  for (int g = 0; g < 2; ++g) {
    const int idx = (tid + g * 256) * 8;
    const int r = idx >> 6, f0 = idx & 63;
    const uint16_t* base = P + (uint64_t)(n0 + r) * 256 + b * 64 + f0;
    float acc8[8] = {};
#pragma unroll
    for (int sp = 0; sp < 8; ++sp) {
      u32x4 v = *(const u32x4*)(base + (uint64_t)sp * 2097152);
#pragma unroll
      for (int j = 0; j < 4; ++j) {
        acc8[2 * j]     += bf2f(v[j] & 0xffffu);
        acc8[2 * j + 1] += bf2f(v[j] >> 16);
      }
    }
#pragma unroll
    for (int j = 0; j < 8; ++j) rows[r][f0 + j] = fmaxf(acc8[j], 0.0f);
  }
  __syncthreads();
  const int nl = tid & 63, g0 = (tid >> 6) * 16;
  float s[16];
#pragma unroll
  for (int j = 0; j < 16; ++j) s[j] = 0.f;
  for (int f = 0; f < 64; ++f) {
    float rv = rows[nl][f];
#pragma unroll
    for (int j = 0; j < 16; ++j) s[j] = fmaf(rv, Wl[f * 64 + g0 + j], s[j]);
  }
  uint16_t* dst = Zt + (uint64_t)(b * 64 + g0) * MK + n0 + nl;
#pragma unroll
  for (int j = 0; j < 16; ++j) dst[(uint64_t)j * MK] = f2bf(s[j]);
}

// ---------------- combineF: out = relu(sum_s P[s] (bf16)) -> f32 [4][8192][64] ------------
__global__ __launch_bounds__(256) void combineF(const uint16_t* __restrict__ P,
                                                float* __restrict__ out) {
  const uint64_t e = ((uint64_t)blockIdx.x * 256 + threadIdx.x) * 8;
  float acc8[8] = {};
#pragma unroll
  for (int sp = 0; sp < 8; ++sp) {
    u32x4 v = *(const u32x4*)&P[(uint64_t)sp * 2097152 + e];
#pragma unroll
    for (int j = 0; j < 4; ++j) {
      acc8[2 * j]     += bf2f(v[j] & 0xffffu);
      acc8[2 * j + 1] += bf2f(v[j] >> 16);
    }
  }
  const int m = (int)(e >> 8);
  const int c = (int)(e & 255);
  float* dst = &out[(((uint64_t)(c >> 6)) * MK + m) * 64 + (c & 63)];
  f32x4 w0, w1;
#pragma unroll
  for (int j = 0; j < 4; ++j) { w0[j] = fmaxf(acc8[j], 0.0f); w1[j] = fmaxf(acc8[4 + j], 0.0f); }
  *(f32x4*)dst = w0;
  *(f32x4*)(dst + 4) = w1;
}

extern "C" void kernel_launch(void* const* d_in, const int* in_sizes, int n_in,
                              void* d_out, int out_size, void* d_ws, size_t ws_size,
                              hipStream_t stream) {
  const float* x   = (const float*)d_in[0];
  const float* net = (const float*)d_in[2];
  const float* A   = (const float*)d_in[3];
  float* out = (float*)d_out;

  uint16_t* Ab = (uint16_t*)d_ws;                               // 128 MiB (chunk-blocked)
  uint16_t* Zt = (uint16_t*)((char*)d_ws + 134217728ull);       // 4 MiB
  uint16_t* P  = (uint16_t*)((char*)d_ws + 142606336ull);       // 32 MiB (bf16 [8][8192][256])

  zw0<<<dim3(128, 4), dim3(256), 0, stream>>>(x, net, Zt);
  gemm1<<<dim3(256), dim3(512), 0, stream>>>(A, Zt, Ab, P);
  zw1P<<<dim3(128, 4), dim3(256), 0, stream>>>(P, net, Zt);
  gemm2<<<dim3(256), dim3(512), 0, stream>>>(Ab, Zt, P);
  combineF<<<dim3(1024), dim3(256), 0, stream>>>(P, out);
}